// Round 1
// 9757.259 us; speedup vs baseline: 1.0481x; 1.0481x over previous
//
#include <hip/hip_runtime.h>
#include <hip/hip_bf16.h>
#include <math.h>

#define B_  256
#define T_  256
#define IN_ 4
#define HP_ 64
#define E_  512
#define H_  1024
#define D_  4

typedef __hip_bfloat16 bf16;

// ---------------------------------------------------------------------------
// Dual-dtype load helpers: flag!=0 -> input arrays are bf16, else fp32.
// bf16 -> f32 via exact bit shift.
// ---------------------------------------------------------------------------
__device__ __forceinline__ float load1(const void* p, size_t idx, bool isb) {
    if (isb) {
        unsigned int u = ((const unsigned short*)p)[idx];
        return __uint_as_float(u << 16);
    }
    return ((const float*)p)[idx];
}

__device__ __forceinline__ float4 load4(const void* p, size_t idx, bool isb) {
    // idx must be a multiple of 4 (8B-aligned bf16 path, 16B-aligned f32 path)
    if (isb) {
        ushort4 u = *(const ushort4*)((const unsigned short*)p + idx);
        float4 r;
        r.x = __uint_as_float(((unsigned int)u.x) << 16);
        r.y = __uint_as_float(((unsigned int)u.y) << 16);
        r.z = __uint_as_float(((unsigned int)u.z) << 16);
        r.w = __uint_as_float(((unsigned int)u.w) << 16);
        return r;
    }
    return *((const float4*)p + (idx >> 2));
}

// ---------------------------------------------------------------------------
// Dtype sniff: reinterpret first 64K ushorts of hist_feat as bf16. Real fp32
// data -> even-indexed ushorts are random mantissa bits -> ~20%+ insane
// magnitudes. Real bf16 N(0,1) data -> none. flag: 1 = bf16, 0 = fp32.
// ---------------------------------------------------------------------------
__global__ void sniff_kernel(const unsigned short* __restrict__ p,
                             int* __restrict__ flag) {
    __shared__ int cnt;
    if (threadIdx.x == 0) cnt = 0;
    __syncthreads();
    int local = 0;
    for (int i = threadIdx.x; i < 65536; i += blockDim.x) {
        unsigned int bits = ((unsigned int)p[i]) << 16;
        float v = __uint_as_float(bits);
        float a = fabsf(v);
        if (!(a <= 1e4f)) local++;                  // huge or NaN
        else if (v != 0.0f && a < 1e-6f) local++;   // absurdly tiny
    }
    atomicAdd(&cnt, local);
    __syncthreads();
    if (threadIdx.x == 0) *flag = (cnt > 1024) ? 0 : 1;
}

// ---------------------------------------------------------------------------
// Projector: Xc[m,:] = gelu(hist[gm,:] @ pW1 + pb1, exact) @ pW2 + pb2
// One block per chunk-local row m; gm = m0 + m is the global (b*T+t) row.
// ---------------------------------------------------------------------------
__global__ __launch_bounds__(256) void proj_kernel(
        const void* __restrict__ hist, const void* __restrict__ pW1,
        const void* __restrict__ pb1,  const void* __restrict__ pW2,
        const void* __restrict__ pb2,  float* __restrict__ Xc,
        size_t m0, const int* __restrict__ flag) {
    const bool isb = (*flag != 0);
    __shared__ float h1[HP_];
    __shared__ float hrow[IN_];
    size_t m = blockIdx.x;
    size_t gm = m0 + m;
    int tid = threadIdx.x;
    if (tid < IN_) hrow[tid] = load1(hist, gm * IN_ + tid, isb);
    __syncthreads();
    if (tid < HP_) {
        float acc = 0.f;
        #pragma unroll
        for (int i = 0; i < IN_; ++i)
            acc = fmaf(hrow[i], load1(pW1, (size_t)i * HP_ + tid, isb), acc);
        acc += load1(pb1, tid, isb);
        // exact GELU: 0.5*x*(1+erf(x/sqrt(2)))
        h1[tid] = 0.5f * acc * (1.0f + erff(acc * 0.70710678118654752440f));
    }
    __syncthreads();
    for (int e = tid; e < E_; e += 256) {
        float acc = 0.f;
        #pragma unroll 8
        for (int i = 0; i < HP_; ++i)
            acc = fmaf(h1[i], load1(pW2, (size_t)i * E_ + e, isb), acc);
        acc += load1(pb2, e, isb);
        Xc[m * E_ + e] = acc;
    }
}

// ---------------------------------------------------------------------------
// Tiled fp32 GEMM: C[R,N] = A[R,K] @ W[K,N] + bias.  128x128 tile, BK=16,
// 256 threads, 8x8 micro-tile (4 FMA per LDS float -> VALU-bound, not
// LDS-bound like the old 64x64/4x4).  Accumulation per output element is
// one fmaf per k in ascending k order + bias add afterwards: BIT-IDENTICAL
// to the previous kernel's numerics.
// ---------------------------------------------------------------------------
__global__ __launch_bounds__(256) void gemm_bias_kernel(
        const float* __restrict__ A, const void* __restrict__ W, size_t wOff,
        const void* __restrict__ bias, size_t bOff,
        float* __restrict__ C, int N, int K, const int* __restrict__ flag) {
    const bool isb = (*flag != 0);
    __shared__ float As[16][128];      // k-major A tile (transposed on store)
    __shared__ float Bs[16][132];      // +4 pad: kills stride-128 write conflicts
    const int bn = blockIdx.x * 128;
    const int bm = blockIdx.y * 128;
    const int tid = threadIdx.x;

    // staging indices
    const int ar = tid >> 1;           // 0..127 : A tile row
    const int ak = (tid & 1) << 3;     // 0 or 8 : A k base (2x float4)
    const int wr = tid >> 4;           // 0..15  : W tile k-row
    const int wc = (tid & 15) << 3;    // 0..120 : W tile col base (2x float4)

    // compute indices (16x16 thread grid, 8x8 microtile each)
    const int tm = (tid >> 4) << 3;    // row base within tile
    const int tn = (tid & 15) << 3;    // col base within tile

    float acc[8][8];
    #pragma unroll
    for (int i = 0; i < 8; ++i)
        #pragma unroll
        for (int j = 0; j < 8; ++j) acc[i][j] = 0.f;

    const float* Ap = A + (size_t)(bm + ar) * K + ak;
    for (int k0 = 0; k0 < K; k0 += 16) {
        float4 a0 = *(const float4*)(Ap + k0);
        float4 a1 = *(const float4*)(Ap + k0 + 4);
        As[ak + 0][ar] = a0.x; As[ak + 1][ar] = a0.y;
        As[ak + 2][ar] = a0.z; As[ak + 3][ar] = a0.w;
        As[ak + 4][ar] = a1.x; As[ak + 5][ar] = a1.y;
        As[ak + 6][ar] = a1.z; As[ak + 7][ar] = a1.w;
        size_t wbase = wOff + (size_t)(wr + k0) * N + bn + wc;
        float4 w0 = load4(W, wbase, isb);
        float4 w1 = load4(W, wbase + 4, isb);
        *(float4*)&Bs[wr][wc]     = w0;
        *(float4*)&Bs[wr][wc + 4] = w1;
        __syncthreads();
        #pragma unroll
        for (int k = 0; k < 16; ++k) {
            float a[8], b[8];
            *(float4*)&a[0] = *(const float4*)&As[k][tm];
            *(float4*)&a[4] = *(const float4*)&As[k][tm + 4];
            *(float4*)&b[0] = *(const float4*)&Bs[k][tn];
            *(float4*)&b[4] = *(const float4*)&Bs[k][tn + 4];
            #pragma unroll
            for (int i = 0; i < 8; ++i)
                #pragma unroll
                for (int j = 0; j < 8; ++j)
                    acc[i][j] = fmaf(a[i], b[j], acc[i][j]);
        }
        __syncthreads();
    }
    #pragma unroll
    for (int i = 0; i < 8; ++i) {
        size_t row = (size_t)(bm + tm + i);
        int col = bn + tn;
        float4 o0, o1;
        o0.x = acc[i][0] + load1(bias, bOff + col + 0, isb);
        o0.y = acc[i][1] + load1(bias, bOff + col + 1, isb);
        o0.z = acc[i][2] + load1(bias, bOff + col + 2, isb);
        o0.w = acc[i][3] + load1(bias, bOff + col + 3, isb);
        o1.x = acc[i][4] + load1(bias, bOff + col + 4, isb);
        o1.y = acc[i][5] + load1(bias, bOff + col + 5, isb);
        o1.z = acc[i][6] + load1(bias, bOff + col + 6, isb);
        o1.w = acc[i][7] + load1(bias, bOff + col + 7, isb);
        *(float4*)(C + row * N + col)     = o0;
        *(float4*)(C + row * N + col + 4) = o1;
    }
}

// ---------------------------------------------------------------------------
// Row-wise LayerNorm, in place. One block (256 thr) per row, two-pass.
// ---------------------------------------------------------------------------
__device__ __forceinline__ float block_sum(float v, float* smem, int tid) {
    #pragma unroll
    for (int off = 32; off > 0; off >>= 1) v += __shfl_down(v, off, 64);
    __syncthreads();
    if ((tid & 63) == 0) smem[tid >> 6] = v;
    __syncthreads();
    if (tid == 0) smem[4] = smem[0] + smem[1] + smem[2] + smem[3];
    __syncthreads();
    return smem[4];
}

__global__ __launch_bounds__(256) void ln_kernel(float* __restrict__ Y,
        const void* __restrict__ g, size_t gOff,
        const void* __restrict__ b, size_t bOff,
        int N, const int* __restrict__ flag) {
    const bool isb = (*flag != 0);
    __shared__ float smem[5];
    size_t row = blockIdx.x;
    float* y = Y + row * (size_t)N;
    int tid = threadIdx.x;
    int nPer = N >> 8;   // 4 for N=1024, 2 for N=512
    float vals[4];
    float s = 0.f;
    for (int i = 0; i < nPer; ++i) { float v = y[tid + (i << 8)]; vals[i] = v; s += v; }
    float mean = block_sum(s, smem, tid) / (float)N;
    float sq = 0.f;
    for (int i = 0; i < nPer; ++i) { float d0 = vals[i] - mean; sq += d0 * d0; }
    float var = block_sum(sq, smem, tid) / (float)N;
    float denom = sqrtf(var + 1e-5f);
    for (int i = 0; i < nPer; ++i) {
        int c = tid + (i << 8);
        y[c] = (vals[i] - mean) / denom * load1(g, gOff + c, isb) + load1(b, bOff + c, isb);
    }
}

// ---------------------------------------------------------------------------
// LIF scan over T, in place. Thread per (local b, feature), coalesced per t.
// v += (x - v)/2 ; s = (v-1 >= 0) ; hard reset v *= (1-s).
// ---------------------------------------------------------------------------
__global__ __launch_bounds__(256) void lif_kernel(float* __restrict__ Y, int N) {
    int f = blockIdx.x * 256 + threadIdx.x;
    int b = blockIdx.y;
    size_t base = (size_t)b * T_ * N + f;
    float v = 0.f;
    for (int t = 0; t < T_; ++t) {
        size_t idx = base + (size_t)t * N;
        float x = Y[idx];
        v = v + (x - v) * 0.5f;
        float s = (v - 1.0f >= 0.0f) ? 1.0f : 0.0f;
        v = v * (1.0f - s);
        Y[idx] = s;
    }
}

// Second LIF of a layer fused with residual add into Xc.
__global__ __launch_bounds__(256) void lif_add_kernel(const float* __restrict__ Z,
                                                      float* __restrict__ Xc) {
    int e = blockIdx.x * 256 + threadIdx.x;
    int b = blockIdx.y;
    size_t base = (size_t)b * T_ * E_ + e;
    float v = 0.f;
    for (int t = 0; t < T_; ++t) {
        size_t idx = base + (size_t)t * E_;
        float x = Z[idx];
        v = v + (x - v) * 0.5f;
        float s = (v - 1.0f >= 0.0f) ? 1.0f : 0.0f;
        v = v * (1.0f - s);
        Xc[idx] += s;
    }
}

// Gather chunk rows t=T-1 -> out[b0+bl, :], encode bf16/fp32 per flag.
__global__ void out_kernel(const float* __restrict__ Xc, void* __restrict__ out,
                           int b0, const int* __restrict__ flag) {
    int i = blockIdx.x * 256 + threadIdx.x;   // 0 .. CB*E_-1
    int bl = i / E_, e = i - bl * E_;
    float v = Xc[((size_t)bl * T_ + (T_ - 1)) * E_ + e];
    size_t oi = (size_t)(b0 + bl) * E_ + e;
    if (*flag) ((bf16*)out)[oi] = __float2bfloat16(v);
    else       ((float*)out)[oi] = v;
}

// ---------------------------------------------------------------------------
extern "C" void kernel_launch(void* const* d_in, const int* in_sizes, int n_in,
                              void* d_out, int out_size, void* d_ws, size_t ws_size,
                              hipStream_t stream) {
    char* ws = (char*)d_ws;
    int* flag = (int*)ws;

    // Chunk over batches so workspace fits: per chunk of CB batches we need
    // CB*T*(E + H + E)*4 bytes = CB * 2 MiB.
    size_t avail = (ws_size > 256) ? ws_size - 256 : 0;
    int CB = 256;
    while (CB > 1 && (size_t)CB * T_ * (size_t)(E_ + H_ + E_) * 4 > avail) CB >>= 1;
    const int R = CB * T_;

    float* Xc  = (float*)(ws + 256);
    float* HBc = Xc + (size_t)R * E_;
    float* Y2c = HBc + (size_t)R * H_;

    sniff_kernel<<<1, 256, 0, stream>>>((const unsigned short*)d_in[0], flag);

    for (int b0 = 0; b0 < B_; b0 += CB) {
        proj_kernel<<<R, 256, 0, stream>>>(d_in[0], d_in[1], d_in[2], d_in[3],
                                           d_in[4], Xc, (size_t)b0 * T_, flag);
        for (int d = 0; d < D_; ++d) {
            size_t w1o = (size_t)d * E_ * H_, b1o = (size_t)d * H_;
            size_t w2o = (size_t)d * H_ * E_, b2o = (size_t)d * E_;

            gemm_bias_kernel<<<dim3(H_ / 128, R / 128), 256, 0, stream>>>(
                Xc, d_in[5], w1o, d_in[6], b1o, HBc, H_, E_, flag);
            ln_kernel<<<R, 256, 0, stream>>>(HBc, d_in[7], b1o, d_in[8], b1o, H_, flag);
            lif_kernel<<<dim3(H_ / 256, CB), 256, 0, stream>>>(HBc, H_);

            gemm_bias_kernel<<<dim3(E_ / 128, R / 128), 256, 0, stream>>>(
                HBc, d_in[9], w2o, d_in[10], b2o, Y2c, E_, H_, flag);
            ln_kernel<<<R, 256, 0, stream>>>(Y2c, d_in[11], b2o, d_in[12], b2o, E_, flag);
            lif_add_kernel<<<dim3(E_ / 256, CB), 256, 0, stream>>>(Y2c, Xc);
        }
        out_kernel<<<(CB * E_) / 256, 256, 0, stream>>>(Xc, d_out, b0, flag);
    }
}

// Round 2
// 9119.666 us; speedup vs baseline: 1.1213x; 1.0699x over previous
//
#include <hip/hip_runtime.h>
#include <hip/hip_bf16.h>
#include <math.h>

#define B_  256
#define T_  256
#define IN_ 4
#define HP_ 64
#define E_  512
#define H_  1024
#define D_  4

typedef __hip_bfloat16 bf16;

// ---------------------------------------------------------------------------
// Dual-dtype load helpers: flag!=0 -> input arrays are bf16, else fp32.
// bf16 -> f32 via exact bit shift.
// ---------------------------------------------------------------------------
__device__ __forceinline__ float load1(const void* p, size_t idx, bool isb) {
    if (isb) {
        unsigned int u = ((const unsigned short*)p)[idx];
        return __uint_as_float(u << 16);
    }
    return ((const float*)p)[idx];
}

__device__ __forceinline__ float4 load4(const void* p, size_t idx, bool isb) {
    // idx must be a multiple of 4 (8B-aligned bf16 path, 16B-aligned f32 path)
    if (isb) {
        ushort4 u = *(const ushort4*)((const unsigned short*)p + idx);
        float4 r;
        r.x = __uint_as_float(((unsigned int)u.x) << 16);
        r.y = __uint_as_float(((unsigned int)u.y) << 16);
        r.z = __uint_as_float(((unsigned int)u.z) << 16);
        r.w = __uint_as_float(((unsigned int)u.w) << 16);
        return r;
    }
    return *((const float4*)p + (idx >> 2));
}

// ---------------------------------------------------------------------------
// Dtype sniff: reinterpret first 64K ushorts of hist_feat as bf16. Real fp32
// data -> even-indexed ushorts are random mantissa bits -> ~20%+ insane
// magnitudes. Real bf16 N(0,1) data -> none. flag: 1 = bf16, 0 = fp32.
// ---------------------------------------------------------------------------
__global__ void sniff_kernel(const unsigned short* __restrict__ p,
                             int* __restrict__ flag) {
    __shared__ int cnt;
    if (threadIdx.x == 0) cnt = 0;
    __syncthreads();
    int local = 0;
    for (int i = threadIdx.x; i < 65536; i += blockDim.x) {
        unsigned int bits = ((unsigned int)p[i]) << 16;
        float v = __uint_as_float(bits);
        float a = fabsf(v);
        if (!(a <= 1e4f)) local++;                  // huge or NaN
        else if (v != 0.0f && a < 1e-6f) local++;   // absurdly tiny
    }
    atomicAdd(&cnt, local);
    __syncthreads();
    if (threadIdx.x == 0) *flag = (cnt > 1024) ? 0 : 1;
}

// ---------------------------------------------------------------------------
// Projector: Xc[m,:] = gelu(hist[gm,:] @ pW1 + pb1, exact) @ pW2 + pb2
// One block per chunk-local row m; gm = m0 + m is the global (b*T+t) row.
// ---------------------------------------------------------------------------
__global__ __launch_bounds__(256) void proj_kernel(
        const void* __restrict__ hist, const void* __restrict__ pW1,
        const void* __restrict__ pb1,  const void* __restrict__ pW2,
        const void* __restrict__ pb2,  float* __restrict__ Xc,
        size_t m0, const int* __restrict__ flag) {
    const bool isb = (*flag != 0);
    __shared__ float h1[HP_];
    __shared__ float hrow[IN_];
    size_t m = blockIdx.x;
    size_t gm = m0 + m;
    int tid = threadIdx.x;
    if (tid < IN_) hrow[tid] = load1(hist, gm * IN_ + tid, isb);
    __syncthreads();
    if (tid < HP_) {
        float acc = 0.f;
        #pragma unroll
        for (int i = 0; i < IN_; ++i)
            acc = fmaf(hrow[i], load1(pW1, (size_t)i * HP_ + tid, isb), acc);
        acc += load1(pb1, tid, isb);
        // exact GELU: 0.5*x*(1+erf(x/sqrt(2)))
        h1[tid] = 0.5f * acc * (1.0f + erff(acc * 0.70710678118654752440f));
    }
    __syncthreads();
    for (int e = tid; e < E_; e += 256) {
        float acc = 0.f;
        #pragma unroll 8
        for (int i = 0; i < HP_; ++i)
            acc = fmaf(h1[i], load1(pW2, (size_t)i * E_ + e, isb), acc);
        acc += load1(pb2, e, isb);
        Xc[m * E_ + e] = acc;
    }
}

// ---------------------------------------------------------------------------
// Tiled fp32 GEMM: C[R,N] = A[R,K] @ W[K,N] + bias.  128x128 tile, BK=16,
// 256 threads, 8x8 micro-tile split as 2x(4 rows) x 2x(4 cols) 64 apart:
//   - Bs reads/writes hit all 32 banks 2-deep (2-way aliasing is free)
//   - As reads are 4-address broadcasts (conflict-free)
// Double-buffered LDS, ONE __syncthreads per k-tile; next tile's global
// loads issue before the FMA block so ~600cy HBM latency hides under
// 1024 FMAs.  Accumulation per output element is one fmaf per k in
// ascending k order + bias add afterwards: BIT-IDENTICAL numerics.
// ---------------------------------------------------------------------------
__global__ __launch_bounds__(256) void gemm_bias_kernel(
        const float* __restrict__ A, const void* __restrict__ W, size_t wOff,
        const void* __restrict__ bias, size_t bOff,
        float* __restrict__ C, int N, int K, const int* __restrict__ flag) {
    const bool isb = (*flag != 0);
    __shared__ float As[2][16][128];   // k-major A tile (transposed on store)
    __shared__ float Bs[2][16][132];   // +4 pad (harmless; stores are uniform)
    const int bn = blockIdx.x * 128;
    const int bm = blockIdx.y * 128;
    const int tid = threadIdx.x;

    // staging indices
    const int ar = tid >> 1;           // 0..127 : A tile row
    const int ak = (tid & 1) << 3;     // 0 or 8 : A k base (2x float4)
    const int wr = tid >> 4;           // 0..15  : W tile k-row

    // compute indices (16x16 thread grid, 2x4 x 2x4 microtile)
    const int tr = tid >> 4;           // 0..15 : row group
    const int tc = tid & 15;           // 0..15 : col group

    float acc[8][8];
    #pragma unroll
    for (int i = 0; i < 8; ++i)
        #pragma unroll
        for (int j = 0; j < 8; ++j) acc[i][j] = 0.f;

    const float* Ap = A + (size_t)(bm + ar) * K + ak;
    const size_t wBase = wOff + (size_t)wr * N + bn + tc * 4;

    // prologue: stage tile 0 into regs
    float4 a0 = *(const float4*)(Ap);
    float4 a1 = *(const float4*)(Ap + 4);
    float4 w0 = load4(W, wBase, isb);
    float4 w1 = load4(W, wBase + 64, isb);

    const int nt = K >> 4;
    for (int t = 0; t < nt; ++t) {
        const int cur = t & 1;
        // write staged regs to LDS buffer `cur`
        As[cur][ak + 0][ar] = a0.x; As[cur][ak + 1][ar] = a0.y;
        As[cur][ak + 2][ar] = a0.z; As[cur][ak + 3][ar] = a0.w;
        As[cur][ak + 4][ar] = a1.x; As[cur][ak + 5][ar] = a1.y;
        As[cur][ak + 6][ar] = a1.z; As[cur][ak + 7][ar] = a1.w;
        *(float4*)&Bs[cur][wr][tc * 4]      = w0;
        *(float4*)&Bs[cur][wr][64 + tc * 4] = w1;
        __syncthreads();
        // issue next tile's global loads (completion awaited at next store)
        if (t + 1 < nt) {
            const int k0 = (t + 1) << 4;
            a0 = *(const float4*)(Ap + k0);
            a1 = *(const float4*)(Ap + k0 + 4);
            w0 = load4(W, wBase + (size_t)k0 * N, isb);
            w1 = load4(W, wBase + (size_t)k0 * N + 64, isb);
        }
        #pragma unroll
        for (int k = 0; k < 16; ++k) {
            float a[8], b[8];
            *(float4*)&a[0] = *(const float4*)&As[cur][k][tr * 4];
            *(float4*)&a[4] = *(const float4*)&As[cur][k][64 + tr * 4];
            *(float4*)&b[0] = *(const float4*)&Bs[cur][k][tc * 4];
            *(float4*)&b[4] = *(const float4*)&Bs[cur][k][64 + tc * 4];
            #pragma unroll
            for (int i = 0; i < 8; ++i)
                #pragma unroll
                for (int j = 0; j < 8; ++j)
                    acc[i][j] = fmaf(a[i], b[j], acc[i][j]);
        }
    }
    #pragma unroll
    for (int ih = 0; ih < 2; ++ih) {
        #pragma unroll
        for (int i4 = 0; i4 < 4; ++i4) {
            const int i = (ih << 2) + i4;
            size_t row = (size_t)(bm + (ih << 6) + tr * 4 + i4);
            #pragma unroll
            for (int jh = 0; jh < 2; ++jh) {
                const int col = bn + (jh << 6) + tc * 4;
                float4 o;
                o.x = acc[i][(jh << 2) + 0] + load1(bias, bOff + col + 0, isb);
                o.y = acc[i][(jh << 2) + 1] + load1(bias, bOff + col + 1, isb);
                o.z = acc[i][(jh << 2) + 2] + load1(bias, bOff + col + 2, isb);
                o.w = acc[i][(jh << 2) + 3] + load1(bias, bOff + col + 3, isb);
                *(float4*)(C + row * N + col) = o;
            }
        }
    }
}

// ---------------------------------------------------------------------------
// Row-wise LayerNorm, in place. One block (256 thr) per row, two-pass.
// ---------------------------------------------------------------------------
__device__ __forceinline__ float block_sum(float v, float* smem, int tid) {
    #pragma unroll
    for (int off = 32; off > 0; off >>= 1) v += __shfl_down(v, off, 64);
    __syncthreads();
    if ((tid & 63) == 0) smem[tid >> 6] = v;
    __syncthreads();
    if (tid == 0) smem[4] = smem[0] + smem[1] + smem[2] + smem[3];
    __syncthreads();
    return smem[4];
}

__global__ __launch_bounds__(256) void ln_kernel(float* __restrict__ Y,
        const void* __restrict__ g, size_t gOff,
        const void* __restrict__ b, size_t bOff,
        int N, const int* __restrict__ flag) {
    const bool isb = (*flag != 0);
    __shared__ float smem[5];
    size_t row = blockIdx.x;
    float* y = Y + row * (size_t)N;
    int tid = threadIdx.x;
    int nPer = N >> 8;   // 4 for N=1024, 2 for N=512
    float vals[4];
    float s = 0.f;
    for (int i = 0; i < nPer; ++i) { float v = y[tid + (i << 8)]; vals[i] = v; s += v; }
    float mean = block_sum(s, smem, tid) / (float)N;
    float sq = 0.f;
    for (int i = 0; i < nPer; ++i) { float d0 = vals[i] - mean; sq += d0 * d0; }
    float var = block_sum(sq, smem, tid) / (float)N;
    float denom = sqrtf(var + 1e-5f);
    for (int i = 0; i < nPer; ++i) {
        int c = tid + (i << 8);
        y[c] = (vals[i] - mean) / denom * load1(g, gOff + c, isb) + load1(b, bOff + c, isb);
    }
}

// ---------------------------------------------------------------------------
// LIF scan over T, in place. Thread per (local b, feature), coalesced per t.
// v += (x - v)/2 ; s = (v-1 >= 0) ; hard reset v *= (1-s).
// ---------------------------------------------------------------------------
__global__ __launch_bounds__(256) void lif_kernel(float* __restrict__ Y, int N) {
    int f = blockIdx.x * 256 + threadIdx.x;
    int b = blockIdx.y;
    size_t base = (size_t)b * T_ * N + f;
    float v = 0.f;
    for (int t = 0; t < T_; ++t) {
        size_t idx = base + (size_t)t * N;
        float x = Y[idx];
        v = v + (x - v) * 0.5f;
        float s = (v - 1.0f >= 0.0f) ? 1.0f : 0.0f;
        v = v * (1.0f - s);
        Y[idx] = s;
    }
}

// Second LIF of a layer fused with residual add into Xc.
__global__ __launch_bounds__(256) void lif_add_kernel(const float* __restrict__ Z,
                                                      float* __restrict__ Xc) {
    int e = blockIdx.x * 256 + threadIdx.x;
    int b = blockIdx.y;
    size_t base = (size_t)b * T_ * E_ + e;
    float v = 0.f;
    for (int t = 0; t < T_; ++t) {
        size_t idx = base + (size_t)t * E_;
        float x = Z[idx];
        v = v + (x - v) * 0.5f;
        float s = (v - 1.0f >= 0.0f) ? 1.0f : 0.0f;
        v = v * (1.0f - s);
        Xc[idx] += s;
    }
}

// Gather chunk rows t=T-1 -> out[b0+bl, :], encode bf16/fp32 per flag.
__global__ void out_kernel(const float* __restrict__ Xc, void* __restrict__ out,
                           int b0, const int* __restrict__ flag) {
    int i = blockIdx.x * 256 + threadIdx.x;   // 0 .. CB*E_-1
    int bl = i / E_, e = i - bl * E_;
    float v = Xc[((size_t)bl * T_ + (T_ - 1)) * E_ + e];
    size_t oi = (size_t)(b0 + bl) * E_ + e;
    if (*flag) ((bf16*)out)[oi] = __float2bfloat16(v);
    else       ((float*)out)[oi] = v;
}

// ---------------------------------------------------------------------------
extern "C" void kernel_launch(void* const* d_in, const int* in_sizes, int n_in,
                              void* d_out, int out_size, void* d_ws, size_t ws_size,
                              hipStream_t stream) {
    char* ws = (char*)d_ws;
    int* flag = (int*)ws;

    // Chunk over batches so workspace fits: per chunk of CB batches we need
    // CB*T*(E + H + E)*4 bytes = CB * 2 MiB.
    size_t avail = (ws_size > 256) ? ws_size - 256 : 0;
    int CB = 256;
    while (CB > 1 && (size_t)CB * T_ * (size_t)(E_ + H_ + E_) * 4 > avail) CB >>= 1;
    const int R = CB * T_;

    float* Xc  = (float*)(ws + 256);
    float* HBc = Xc + (size_t)R * E_;
    float* Y2c = HBc + (size_t)R * H_;

    sniff_kernel<<<1, 256, 0, stream>>>((const unsigned short*)d_in[0], flag);

    for (int b0 = 0; b0 < B_; b0 += CB) {
        proj_kernel<<<R, 256, 0, stream>>>(d_in[0], d_in[1], d_in[2], d_in[3],
                                           d_in[4], Xc, (size_t)b0 * T_, flag);
        for (int d = 0; d < D_; ++d) {
            size_t w1o = (size_t)d * E_ * H_, b1o = (size_t)d * H_;
            size_t w2o = (size_t)d * H_ * E_, b2o = (size_t)d * E_;

            gemm_bias_kernel<<<dim3(H_ / 128, R / 128), 256, 0, stream>>>(
                Xc, d_in[5], w1o, d_in[6], b1o, HBc, H_, E_, flag);
            ln_kernel<<<R, 256, 0, stream>>>(HBc, d_in[7], b1o, d_in[8], b1o, H_, flag);
            lif_kernel<<<dim3(H_ / 256, CB), 256, 0, stream>>>(HBc, H_);

            gemm_bias_kernel<<<dim3(E_ / 128, R / 128), 256, 0, stream>>>(
                HBc, d_in[9], w2o, d_in[10], b2o, Y2c, E_, H_, flag);
            ln_kernel<<<R, 256, 0, stream>>>(Y2c, d_in[11], b2o, d_in[12], b2o, E_, flag);
            lif_add_kernel<<<dim3(E_ / 256, CB), 256, 0, stream>>>(Y2c, Xc);
        }
        out_kernel<<<(CB * E_) / 256, 256, 0, stream>>>(Xc, d_out, b0, flag);
    }
}